// Round 14
// baseline (164.087 us; speedup 1.0000x reference)
//
#include <hip/hip_runtime.h>
#include <hip/hip_bf16.h>

using u16 = unsigned short;
typedef __attribute__((ext_vector_type(8))) short short8;   // 8 bf16 = 4 VGPR
typedef __attribute__((ext_vector_type(4))) float f32x4;

constexpr int Bc = 2, Sc = 1024, Ec = 1024, Hc = 16, HDc = 64;
constexpr float SCALE = 0.125f; // HD^-0.5

// f32 -> bf16 round-to-nearest-even
__device__ __forceinline__ u16 f2bf(float f) {
    union { float f; unsigned u; } v{f};
    unsigned r = v.u + 0x7FFF + ((v.u >> 16) & 1);
    return (u16)(r >> 16);
}
__device__ __forceinline__ float bf2f(u16 x) {
    union { unsigned u; float f; } v; v.u = ((unsigned)x) << 16; return v.f;
}

// ---------------------------------------------------------------------------
// P0 (merged): bid<2560 -> f32->bf16 copies of Q/K/Wo; bid>=2560 -> V transpose
// into Vt[bh][d=64][S=1024] bf16. grid 3072, block 256.
// ---------------------------------------------------------------------------
__global__ __launch_bounds__(256) void k_prep(
    const float* __restrict__ Q, const float* __restrict__ K,
    const float* __restrict__ Wo, const float* __restrict__ V,
    u16* __restrict__ Qb, u16* __restrict__ Kb, u16* __restrict__ Wob,
    u16* __restrict__ Vt)
{
    __shared__ float tile[64][65];
    const int bid = blockIdx.x;
    const int tid = threadIdx.x;

    if (bid < 2560) {
        const float* src; u16* dst; int base;
        if (bid < 1024)      { src = Q;  dst = Qb;  base = bid; }
        else if (bid < 2048) { src = K;  dst = Kb;  base = bid - 1024; }
        else                 { src = Wo; dst = Wob; base = bid - 2048; }
        const int i = (base * 256 + tid) * 8;
        float4 a = *(const float4*)&src[i];
        float4 b = *(const float4*)&src[i + 4];
        u16 t[8] = {f2bf(a.x), f2bf(a.y), f2bf(a.z), f2bf(a.w),
                    f2bf(b.x), f2bf(b.y), f2bf(b.z), f2bf(b.w)};
        *(short8*)&dst[i] = *(short8*)t;
        return;
    }

    const int bx = bid - 2560;           // 0..511
    const int bh = bx >> 4;
    const int k0 = (bx & 15) * 64;
    const float* Vp = V + (size_t)bh * Sc * HDc + (size_t)k0 * HDc;

    #pragma unroll
    for (int it = 0; it < 4; ++it) {
        int idx = tid + it * 256;
        int k = idx >> 4, d4 = idx & 15;
        float4 v = *(const float4*)&Vp[k * HDc + d4 * 4];
        tile[d4 * 4 + 0][k] = v.x;
        tile[d4 * 4 + 1][k] = v.y;
        tile[d4 * 4 + 2][k] = v.z;
        tile[d4 * 4 + 3][k] = v.w;
    }
    __syncthreads();

    u16* Op = Vt + (size_t)bh * HDc * Sc + k0;
    #pragma unroll
    for (int it = 0; it < 4; ++it) {
        int idx = tid + it * 256;
        int d = idx >> 4, kq = idx & 15;
        u16 t[4];
        #pragma unroll
        for (int j = 0; j < 4; ++j) t[j] = f2bf(tile[d][kq * 4 + j]);
        *(uint2*)&Op[(size_t)d * Sc + kq * 4] = *(uint2*)t;
    }
}

// ---------------------------------------------------------------------------
// K1: scores + aid-mixer, ALL 16 HEADS per block; aid in regs read once.
// ZERO LDS, ZERO BARRIERS: MFMA A-frag (Q) and B-frags (K) loaded directly
// from L2 per head (2 + 8 short8 loads/lane). Waves fully independent ->
// heads pipeline. T1 XCD swizzle retained. NT stores for pre.
// grid 512 = B*16*16, block 256 = 4 waves.
// ---------------------------------------------------------------------------
__global__ __launch_bounds__(256, 2) void k_scores(
    const u16* __restrict__ Qb, const u16* __restrict__ Kb,
    const float* __restrict__ aid, const float* __restrict__ mw,
    const float* __restrict__ mb, const float* __restrict__ ascale,
    float* __restrict__ pre)
{
    const int lbid = (blockIdx.x & 7) * 64 + (blockIdx.x >> 3);  // T1 swizzle
    const int kt = lbid & 15;
    const int qt = (lbid >> 4) & 15;
    const int b  = lbid >> 8;

    const int tid = threadIdx.x;
    const int w = tid >> 6, lane = tid & 63;
    const int lrow = lane & 15, lhi = lane >> 4;

    // aid -> regs. Positions match MFMA C-layout:
    //   rows q = qt*64 + w*16 + lhi*4 + r  (r=0..3)
    //   cols k = kt*64 + fk*16 + lrow      (fk=0..3)
    float a3[4][4][3];
    #pragma unroll
    for (int r = 0; r < 4; ++r) {
        const size_t qg = (size_t)(b * Sc + qt * 64 + w * 16 + lhi * 4 + r) * Sc;
        #pragma unroll
        for (int fk = 0; fk < 4; ++fk) {
            const float* ap = aid + (qg + kt * 64 + fk * 16 + lrow) * 3;
            float2 t2 = *(const float2*)ap;
            a3[r][fk][0] = t2.x; a3[r][fk][1] = t2.y; a3[r][fk][2] = ap[2];
        }
    }

    const float asc = ascale[0];
    // A-frag source: this thread's Q row (qt*64 + w*16 + lrow)
    const u16* Qrow = Qb + ((size_t)b * Hc * Sc + qt * 64 + w * 16 + lrow) * HDc;
    // B-frag sources: K rows kt*64 + fk*16 + lrow
    const u16* Kbase = Kb + ((size_t)b * Hc * Sc + kt * 64 + lrow) * HDc;

    for (int h = 0; h < Hc; ++h) {
        const u16* qp = Qrow + (size_t)h * Sc * HDc;
        short8 aq0 = *(const short8*)&qp[lhi * 8];
        short8 aq1 = *(const short8*)&qp[32 + lhi * 8];
        const u16* kp = Kbase + (size_t)h * Sc * HDc;

        f32x4 acc[4] = {};
        #pragma unroll
        for (int fk = 0; fk < 4; ++fk) {
            const u16* kr = kp + (size_t)(fk * 16) * HDc;
            short8 b0 = *(const short8*)&kr[lhi * 8];
            short8 b1 = *(const short8*)&kr[32 + lhi * 8];
            acc[fk] = __builtin_amdgcn_mfma_f32_16x16x32_bf16(aq0, b0, acc[fk], 0, 0, 0);
            acc[fk] = __builtin_amdgcn_mfma_f32_16x16x32_bf16(aq1, b1, acc[fk], 0, 0, 0);
        }

        const float w0 = mw[h * 4 + 0], w1 = mw[h * 4 + 1];
        const float w2 = mw[h * 4 + 2], w3 = mw[h * 4 + 3];
        const float bias = mb[h];
        float* prow0 = pre + ((size_t)(b * Hc + h) * Sc + qt * 64 + w * 16 + lhi * 4) * Sc
                     + kt * 64 + lrow;
        #pragma unroll
        for (int r = 0; r < 4; ++r) {
            #pragma unroll
            for (int fk = 0; fk < 4; ++fk) {
                float s = acc[fk][r] * SCALE;
                float mm = s * w0 + a3[r][fk][0] * w1 + a3[r][fk][1] * w2
                         + a3[r][fk][2] * w3 + bias;
                __builtin_nontemporal_store(s + fmaxf(mm, 0.f) * asc,
                                            &prow0[(size_t)r * Sc + fk * 16]);
            }
        }
    }
}

// ---------------------------------------------------------------------------
// K2: fused softmax + attn-write + PV, 32-row bands, EXP-ONCE.
// T1 swizzle; NT loads for pre, NT stores for attn (via f32x4 ext-vector).
// ---------------------------------------------------------------------------
__global__ __launch_bounds__(512, 4) void k_spv(
    const float* __restrict__ pre, const u16* __restrict__ Vt,
    float* __restrict__ attn, u16* __restrict__ Omid)
{
    __shared__ u16 band[32 * 1024];       // 64 KiB; f32 overlay at the end
    __shared__ float s_m[32];
    __shared__ float s_lp[4][32];         // per-kf partial row sums

    const int lbid = (blockIdx.x & 7) * 128 + (blockIdx.x >> 3);  // T1 swizzle
    const int bh  = lbid >> 5;
    const int qt  = (lbid & 31) * 32;
    const int b   = bh >> 4, h = bh & 15;

    const int tid  = threadIdx.x;
    const int w    = tid >> 6, lane = tid & 63;
    const int lrow = lane & 15, lhi = lane >> 4;

    // ---------------- Phase A: stream pre, track max, fill band ----------
    const int arow = tid >> 4;            // 0..31
    const int s16  = tid & 15;
    const int g    = s16 & 7;
    const int kh   = s16 >> 3;
    const int asw  = arow & 7;
    const float* prow = pre + ((size_t)bh * Sc + qt + arow) * Sc;
    float m = -1e30f;
    #pragma unroll
    for (int k2 = 0; k2 < 8; ++k2) {
        const int kt = kh * 8 + k2;
        const f32x4* p0 = (const f32x4*)(prow + kt * 64 + g * 8);
        f32x4 sa = __builtin_nontemporal_load(p0);
        f32x4 sb = __builtin_nontemporal_load(p0 + 1);
        float s[8];
        *(f32x4*)&s[0] = sa;
        *(f32x4*)&s[4] = sb;
        u16 t[8];
        #pragma unroll
        for (int j = 0; j < 8; ++j) { m = fmaxf(m, s[j]); t[j] = f2bf(s[j]); }
        *(short8*)&band[arow * 1024 + (kt * 8 + (g ^ asw)) * 8] = *(short8*)t;
    }
    m = fmaxf(m, __shfl_xor(m, 1));
    m = fmaxf(m, __shfl_xor(m, 2));
    m = fmaxf(m, __shfl_xor(m, 4));
    m = fmaxf(m, __shfl_xor(m, 8));
    if (s16 == 0) s_m[arow] = m;
    __syncthreads();

    // ------- Phase B: exp once, write back, partial l, PV accumulate -----
    const int rf = w & 1, kf = w >> 1;    // row-frag 0..1, k-range 0..3
    const int brow = rf * 16 + lrow;
    const int bsw  = brow & 7;
    const float mreg = s_m[brow];
    const u16* Vbase = Vt + (size_t)bh * HDc * Sc;
    float l = 0.f;
    f32x4 acc[4] = {};

    #pragma unroll
    for (int j = 0; j < 4; ++j) {
        const int kt = kf * 4 + j;
        const int soA = brow * 1024 + (kt * 8 + (lhi ^ bsw)) * 8;
        const int soB = brow * 1024 + (kt * 8 + ((lhi + 4) ^ bsw)) * 8;
        short8 ra = *(const short8*)&band[soA];
        short8 rb = *(const short8*)&band[soB];
        u16 ea[8], eb[8];
        #pragma unroll
        for (int jj = 0; jj < 8; ++jj) {
            float va = __expf(bf2f((u16)ra[jj]) - mreg); l += va; ea[jj] = f2bf(va);
            float vb = __expf(bf2f((u16)rb[jj]) - mreg); l += vb; eb[jj] = f2bf(vb);
        }
        *(short8*)&band[soA] = *(short8*)ea;   // write exp'd values back
        *(short8*)&band[soB] = *(short8*)eb;
        short8 A0 = *(short8*)ea, A1 = *(short8*)eb;
        #pragma unroll
        for (int fd = 0; fd < 4; ++fd) {
            const u16* vp = Vbase + (size_t)(fd * 16 + lrow) * Sc + kt * 64;
            short8 b0 = *(const short8*)&vp[lhi * 8];
            short8 b1 = *(const short8*)&vp[(lhi + 4) * 8];
            acc[fd] = __builtin_amdgcn_mfma_f32_16x16x32_bf16(A0, b0, acc[fd], 0, 0, 0);
            acc[fd] = __builtin_amdgcn_mfma_f32_16x16x32_bf16(A1, b1, acc[fd], 0, 0, 0);
        }
    }
    l += __shfl_xor(l, 16);
    l += __shfl_xor(l, 32);
    if (lhi == 0) s_lp[kf][brow] = l;
    __syncthreads();                      // exp'd band + s_lp visible

    // ---------------- Phase C: attn = band * inv (no exp) ----------------
    const float lt = s_lp[0][arow] + s_lp[1][arow] + s_lp[2][arow] + s_lp[3][arow];
    const float inv = 1.f / lt;
    float* arowp = attn + ((size_t)bh * Sc + qt + arow) * Sc;
    #pragma unroll
    for (int k2 = 0; k2 < 8; ++k2) {
        const int kt = kh * 8 + k2;
        short8 ra = *(const short8*)&band[arow * 1024 + (kt * 8 + (g ^ asw)) * 8];
        float o[8];
        #pragma unroll
        for (int jj = 0; jj < 8; ++jj) o[jj] = bf2f((u16)ra[jj]) * inv;
        __builtin_nontemporal_store(*(f32x4*)&o[0], (f32x4*)&arowp[kt * 64 + g * 8]);
        __builtin_nontemporal_store(*(f32x4*)&o[4], (f32x4*)&arowp[kt * 64 + g * 8 + 4]);
    }
    __syncthreads();                      // band reads done -> reuse as overlay

    // ---------------- O reduce across kf (overlay) and write -------------
    float* ovl = (float*)band;            // [kf][32 rows][stride 68]
    #pragma unroll
    for (int reg = 0; reg < 4; ++reg) {
        const int rowO = rf * 16 + lhi * 4 + reg;
        #pragma unroll
        for (int fd = 0; fd < 4; ++fd)
            ovl[(kf * 32 + rowO) * 68 + fd * 16 + lrow] = acc[fd][reg];
    }
    __syncthreads();

    const int orow_ = tid >> 4;           // 0..31
    const int dq    = tid & 15;           // 4 d per thread
    const float lr = 1.f / (s_lp[0][orow_] + s_lp[1][orow_]
                          + s_lp[2][orow_] + s_lp[3][orow_]);
    u16 t4[4];
    #pragma unroll
    for (int dd = 0; dd < 4; ++dd) {
        const int d = dq * 4 + dd;
        float v = ovl[(0 * 32 + orow_) * 68 + d] + ovl[(1 * 32 + orow_) * 68 + d]
                + ovl[(2 * 32 + orow_) * 68 + d] + ovl[(3 * 32 + orow_) * 68 + d];
        t4[dd] = f2bf(v * lr);
    }
    *(uint2*)&Omid[((size_t)b * Sc + qt + orow_) * Ec + h * HDc + dq * 4] = *(uint2*)t4;
}

// ---------------------------------------------------------------------------
// K4: out = Omid @ Wo^T + bo (f32 out). T1 swizzle (256 blocks, 32/XCD).
// ---------------------------------------------------------------------------
__global__ __launch_bounds__(256, 2) void k_proj(
    const u16* __restrict__ Ob, const u16* __restrict__ Wob,
    const float* __restrict__ bo, float* __restrict__ out)
{
    __shared__ u16 Xs[128 * 64];
    __shared__ u16 Ws[64 * 64];

    const int lbid = (blockIdx.x & 7) * 32 + (blockIdx.x >> 3);  // T1 swizzle
    const int mt = (lbid >> 4) * 128;
    const int et = (lbid & 15) * 64;

    const int tid = threadIdx.x;
    const int w = tid >> 6, lane = tid & 63;
    const int lrow = lane & 15, lhi = lane >> 4;

    f32x4 acc[2][4] = {};

    for (int kb = 0; kb < Ec; kb += 64) {
        #pragma unroll
        for (int it = 0; it < 4; ++it) {
            int idx = tid + it * 256;
            int r = idx >> 3, g = idx & 7;
            *(short8*)&Xs[r * 64 + (g ^ (r & 7)) * 8] =
                *(const short8*)&Ob[(size_t)(mt + r) * Ec + kb + g * 8];
        }
        #pragma unroll
        for (int it = 0; it < 2; ++it) {
            int idx = tid + it * 256;
            int r = idx >> 3, g = idx & 7;
            *(short8*)&Ws[r * 64 + (g ^ (r & 7)) * 8] =
                *(const short8*)&Wob[(size_t)(et + r) * Ec + kb + g * 8];
        }
        __syncthreads();

        #pragma unroll
        for (int ks = 0; ks < 2; ++ks) {
            short8 af[2], bfr[4];
            int g = ks * 4 + lhi;
            #pragma unroll
            for (int fq = 0; fq < 2; ++fq) {
                int rq = w * 32 + fq * 16 + lrow;
                af[fq] = *(const short8*)&Xs[rq * 64 + (g ^ (rq & 7)) * 8];
            }
            #pragma unroll
            for (int fd = 0; fd < 4; ++fd) {
                int rv = fd * 16 + lrow;
                bfr[fd] = *(const short8*)&Ws[rv * 64 + (g ^ (rv & 7)) * 8];
            }
            #pragma unroll
            for (int fq = 0; fq < 2; ++fq)
                #pragma unroll
                for (int fd = 0; fd < 4; ++fd)
                    acc[fq][fd] = __builtin_amdgcn_mfma_f32_16x16x32_bf16(
                        af[fq], bfr[fd], acc[fq][fd], 0, 0, 0);
        }
        __syncthreads();
    }

    #pragma unroll
    for (int fq = 0; fq < 2; ++fq)
        #pragma unroll
        for (int r = 0; r < 4; ++r) {
            const int m = mt + w * 32 + fq * 16 + lhi * 4 + r;
            float* orow = out + (size_t)m * Ec + et;
            #pragma unroll
            for (int fd = 0; fd < 4; ++fd) {
                int e = fd * 16 + lrow;
                orow[e] = acc[fq][fd][r] + bo[et + e];
            }
        }
}

// ---------------------------------------------------------------------------
extern "C" void kernel_launch(void* const* d_in, const int* in_sizes, int n_in,
                              void* d_out, int out_size, void* d_ws, size_t ws_size,
                              hipStream_t stream) {
    const float* query  = (const float*)d_in[0];
    const float* key    = (const float*)d_in[1];
    const float* value  = (const float*)d_in[2];
    const float* aid    = (const float*)d_in[3];
    const float* mw     = (const float*)d_in[4];
    const float* mb     = (const float*)d_in[5];
    const float* Wo     = (const float*)d_in[6];
    const float* bo     = (const float*)d_in[7];
    const float* ascale = (const float*)d_in[8];

    float* out_p  = (float*)d_out;                       // (B,S,E)
    float* attn_p = out_p + (size_t)Bc * Sc * Ec;        // (B,H,S,S)
    float* pre_p  = attn_p + (size_t)Bc * Hc * Sc * Sc;  // (B,H,S,S)

    u16* Vtb  = (u16*)d_ws;                        // 2M elems (transposed V)
    u16* Omid = Vtb  + (size_t)2 * 1024 * 1024;    // 2M
    u16* Qb   = Omid + (size_t)2 * 1024 * 1024;    // 2M
    u16* Kb   = Qb   + (size_t)2 * 1024 * 1024;    // 2M
    u16* Wob  = Kb   + (size_t)2 * 1024 * 1024;    // 1M

    k_prep<<<3072, 256, 0, stream>>>(query, key, Wo, value, Qb, Kb, Wob, Vtb);
    k_scores<<<Bc * 16 * 16, 256, 0, stream>>>(Qb, Kb, aid, mw, mb, ascale, pre_p);
    k_spv<<<Bc * Hc * (Sc / 32), 512, 0, stream>>>(pre_p, Vtb, attn_p, Omid);
    k_proj<<<(Bc * Sc / 128) * (Ec / 64), 256, 0, stream>>>(Omid, Wob, bo, out_p);
}

// Round 15
// 157.362 us; speedup vs baseline: 1.0427x; 1.0427x over previous
//
#include <hip/hip_runtime.h>
#include <hip/hip_bf16.h>

using u16 = unsigned short;
typedef __attribute__((ext_vector_type(8))) short short8;   // 8 bf16 = 4 VGPR
typedef __attribute__((ext_vector_type(4))) float f32x4;

constexpr int Bc = 2, Sc = 1024, Ec = 1024, Hc = 16, HDc = 64;
constexpr float SCALE = 0.125f; // HD^-0.5

// f32 -> bf16 round-to-nearest-even
__device__ __forceinline__ u16 f2bf(float f) {
    union { float f; unsigned u; } v{f};
    unsigned r = v.u + 0x7FFF + ((v.u >> 16) & 1);
    return (u16)(r >> 16);
}
__device__ __forceinline__ float bf2f(u16 x) {
    union { unsigned u; float f; } v; v.u = ((unsigned)x) << 16; return v.f;
}

// ---------------------------------------------------------------------------
// P0 (merged): bid<2560 -> f32->bf16 copies of Q/K/Wo; bid>=2560 -> V transpose
// into Vt[bh][d=64][S=1024] bf16. grid 3072, block 256.
// ---------------------------------------------------------------------------
__global__ __launch_bounds__(256) void k_prep(
    const float* __restrict__ Q, const float* __restrict__ K,
    const float* __restrict__ Wo, const float* __restrict__ V,
    u16* __restrict__ Qb, u16* __restrict__ Kb, u16* __restrict__ Wob,
    u16* __restrict__ Vt)
{
    __shared__ float tile[64][65];
    const int bid = blockIdx.x;
    const int tid = threadIdx.x;

    if (bid < 2560) {
        const float* src; u16* dst; int base;
        if (bid < 1024)      { src = Q;  dst = Qb;  base = bid; }
        else if (bid < 2048) { src = K;  dst = Kb;  base = bid - 1024; }
        else                 { src = Wo; dst = Wob; base = bid - 2048; }
        const int i = (base * 256 + tid) * 8;
        float4 a = *(const float4*)&src[i];
        float4 b = *(const float4*)&src[i + 4];
        u16 t[8] = {f2bf(a.x), f2bf(a.y), f2bf(a.z), f2bf(a.w),
                    f2bf(b.x), f2bf(b.y), f2bf(b.z), f2bf(b.w)};
        *(short8*)&dst[i] = *(short8*)t;
        return;
    }

    const int bx = bid - 2560;           // 0..511
    const int bh = bx >> 4;
    const int k0 = (bx & 15) * 64;
    const float* Vp = V + (size_t)bh * Sc * HDc + (size_t)k0 * HDc;

    #pragma unroll
    for (int it = 0; it < 4; ++it) {
        int idx = tid + it * 256;
        int k = idx >> 4, d4 = idx & 15;
        float4 v = *(const float4*)&Vp[k * HDc + d4 * 4];
        tile[d4 * 4 + 0][k] = v.x;
        tile[d4 * 4 + 1][k] = v.y;
        tile[d4 * 4 + 2][k] = v.z;
        tile[d4 * 4 + 3][k] = v.w;
    }
    __syncthreads();

    u16* Op = Vt + (size_t)bh * HDc * Sc + k0;
    #pragma unroll
    for (int it = 0; it < 4; ++it) {
        int idx = tid + it * 256;
        int d = idx >> 4, kq = idx & 15;
        u16 t[4];
        #pragma unroll
        for (int j = 0; j < 4; ++j) t[j] = f2bf(tile[d][kq * 4 + j]);
        *(uint2*)&Op[(size_t)d * Sc + kq * 4] = *(uint2*)t;
    }
}

// ---------------------------------------------------------------------------
// K1: scores + aid-mixer, ALL 16 HEADS per block; aid in regs read once.
// ZERO LDS, ZERO BARRIERS: MFMA A-frag (Q) and B-frags (K) loaded directly
// from L2 per head. Normal (cached) stores for pre — NT proved harmful (r14).
// T1 XCD swizzle. grid 512 = B*16*16, block 256 = 4 waves.
// ---------------------------------------------------------------------------
__global__ __launch_bounds__(256, 2) void k_scores(
    const u16* __restrict__ Qb, const u16* __restrict__ Kb,
    const float* __restrict__ aid, const float* __restrict__ mw,
    const float* __restrict__ mb, const float* __restrict__ ascale,
    float* __restrict__ pre)
{
    const int lbid = (blockIdx.x & 7) * 64 + (blockIdx.x >> 3);  // T1 swizzle
    const int kt = lbid & 15;
    const int qt = (lbid >> 4) & 15;
    const int b  = lbid >> 8;

    const int tid = threadIdx.x;
    const int w = tid >> 6, lane = tid & 63;
    const int lrow = lane & 15, lhi = lane >> 4;

    // aid -> regs. Positions match MFMA C-layout:
    //   rows q = qt*64 + w*16 + lhi*4 + r  (r=0..3)
    //   cols k = kt*64 + fk*16 + lrow      (fk=0..3)
    float a3[4][4][3];
    #pragma unroll
    for (int r = 0; r < 4; ++r) {
        const size_t qg = (size_t)(b * Sc + qt * 64 + w * 16 + lhi * 4 + r) * Sc;
        #pragma unroll
        for (int fk = 0; fk < 4; ++fk) {
            const float* ap = aid + (qg + kt * 64 + fk * 16 + lrow) * 3;
            float2 t2 = *(const float2*)ap;
            a3[r][fk][0] = t2.x; a3[r][fk][1] = t2.y; a3[r][fk][2] = ap[2];
        }
    }

    const float asc = ascale[0];
    // A-frag source: this thread's Q row (qt*64 + w*16 + lrow)
    const u16* Qrow = Qb + ((size_t)b * Hc * Sc + qt * 64 + w * 16 + lrow) * HDc;
    // B-frag sources: K rows kt*64 + fk*16 + lrow
    const u16* Kbase = Kb + ((size_t)b * Hc * Sc + kt * 64 + lrow) * HDc;

    for (int h = 0; h < Hc; ++h) {
        const u16* qp = Qrow + (size_t)h * Sc * HDc;
        short8 aq0 = *(const short8*)&qp[lhi * 8];
        short8 aq1 = *(const short8*)&qp[32 + lhi * 8];
        const u16* kp = Kbase + (size_t)h * Sc * HDc;

        f32x4 acc[4] = {};
        #pragma unroll
        for (int fk = 0; fk < 4; ++fk) {
            const u16* kr = kp + (size_t)(fk * 16) * HDc;
            short8 b0 = *(const short8*)&kr[lhi * 8];
            short8 b1 = *(const short8*)&kr[32 + lhi * 8];
            acc[fk] = __builtin_amdgcn_mfma_f32_16x16x32_bf16(aq0, b0, acc[fk], 0, 0, 0);
            acc[fk] = __builtin_amdgcn_mfma_f32_16x16x32_bf16(aq1, b1, acc[fk], 0, 0, 0);
        }

        const float w0 = mw[h * 4 + 0], w1 = mw[h * 4 + 1];
        const float w2 = mw[h * 4 + 2], w3 = mw[h * 4 + 3];
        const float bias = mb[h];
        float* prow0 = pre + ((size_t)(b * Hc + h) * Sc + qt * 64 + w * 16 + lhi * 4) * Sc
                     + kt * 64 + lrow;
        #pragma unroll
        for (int r = 0; r < 4; ++r) {
            #pragma unroll
            for (int fk = 0; fk < 4; ++fk) {
                float s = acc[fk][r] * SCALE;
                float mm = s * w0 + a3[r][fk][0] * w1 + a3[r][fk][1] * w2
                         + a3[r][fk][2] * w3 + bias;
                prow0[(size_t)r * Sc + fk * 16] = s + fmaxf(mm, 0.f) * asc;
            }
        }
    }
}

// ---------------------------------------------------------------------------
// K2: fused softmax + attn-write + PV, 32-row bands, EXP-ONCE.
// T1 swizzle. Regular cached loads/stores (round-12 proven form).
// ---------------------------------------------------------------------------
__global__ __launch_bounds__(512, 4) void k_spv(
    const float* __restrict__ pre, const u16* __restrict__ Vt,
    float* __restrict__ attn, u16* __restrict__ Omid)
{
    __shared__ u16 band[32 * 1024];       // 64 KiB; f32 overlay at the end
    __shared__ float s_m[32];
    __shared__ float s_lp[4][32];         // per-kf partial row sums

    const int lbid = (blockIdx.x & 7) * 128 + (blockIdx.x >> 3);  // T1 swizzle
    const int bh  = lbid >> 5;
    const int qt  = (lbid & 31) * 32;
    const int b   = bh >> 4, h = bh & 15;

    const int tid  = threadIdx.x;
    const int w    = tid >> 6, lane = tid & 63;
    const int lrow = lane & 15, lhi = lane >> 4;

    // ---------------- Phase A: stream pre, track max, fill band ----------
    const int arow = tid >> 4;            // 0..31
    const int s16  = tid & 15;
    const int g    = s16 & 7;
    const int kh   = s16 >> 3;
    const int asw  = arow & 7;
    const float* prow = pre + ((size_t)bh * Sc + qt + arow) * Sc;
    float m = -1e30f;
    #pragma unroll
    for (int k2 = 0; k2 < 8; ++k2) {
        const int kt = kh * 8 + k2;
        const float* p0 = prow + kt * 64 + g * 8;
        float s[8];
        *(float4*)&s[0] = *(const float4*)p0;
        *(float4*)&s[4] = *(const float4*)(p0 + 4);
        u16 t[8];
        #pragma unroll
        for (int j = 0; j < 8; ++j) { m = fmaxf(m, s[j]); t[j] = f2bf(s[j]); }
        *(short8*)&band[arow * 1024 + (kt * 8 + (g ^ asw)) * 8] = *(short8*)t;
    }
    m = fmaxf(m, __shfl_xor(m, 1));
    m = fmaxf(m, __shfl_xor(m, 2));
    m = fmaxf(m, __shfl_xor(m, 4));
    m = fmaxf(m, __shfl_xor(m, 8));
    if (s16 == 0) s_m[arow] = m;
    __syncthreads();

    // ------- Phase B: exp once, write back, partial l, PV accumulate -----
    const int rf = w & 1, kf = w >> 1;    // row-frag 0..1, k-range 0..3
    const int brow = rf * 16 + lrow;
    const int bsw  = brow & 7;
    const float mreg = s_m[brow];
    const u16* Vbase = Vt + (size_t)bh * HDc * Sc;
    float l = 0.f;
    f32x4 acc[4] = {};

    #pragma unroll
    for (int j = 0; j < 4; ++j) {
        const int kt = kf * 4 + j;
        const int soA = brow * 1024 + (kt * 8 + (lhi ^ bsw)) * 8;
        const int soB = brow * 1024 + (kt * 8 + ((lhi + 4) ^ bsw)) * 8;
        short8 ra = *(const short8*)&band[soA];
        short8 rb = *(const short8*)&band[soB];
        u16 ea[8], eb[8];
        #pragma unroll
        for (int jj = 0; jj < 8; ++jj) {
            float va = __expf(bf2f((u16)ra[jj]) - mreg); l += va; ea[jj] = f2bf(va);
            float vb = __expf(bf2f((u16)rb[jj]) - mreg); l += vb; eb[jj] = f2bf(vb);
        }
        *(short8*)&band[soA] = *(short8*)ea;   // write exp'd values back
        *(short8*)&band[soB] = *(short8*)eb;
        short8 A0 = *(short8*)ea, A1 = *(short8*)eb;
        #pragma unroll
        for (int fd = 0; fd < 4; ++fd) {
            const u16* vp = Vbase + (size_t)(fd * 16 + lrow) * Sc + kt * 64;
            short8 b0 = *(const short8*)&vp[lhi * 8];
            short8 b1 = *(const short8*)&vp[(lhi + 4) * 8];
            acc[fd] = __builtin_amdgcn_mfma_f32_16x16x32_bf16(A0, b0, acc[fd], 0, 0, 0);
            acc[fd] = __builtin_amdgcn_mfma_f32_16x16x32_bf16(A1, b1, acc[fd], 0, 0, 0);
        }
    }
    l += __shfl_xor(l, 16);
    l += __shfl_xor(l, 32);
    if (lhi == 0) s_lp[kf][brow] = l;
    __syncthreads();                      // exp'd band + s_lp visible

    // ---------------- Phase C: attn = band * inv (no exp) ----------------
    const float lt = s_lp[0][arow] + s_lp[1][arow] + s_lp[2][arow] + s_lp[3][arow];
    const float inv = 1.f / lt;
    float* arowp = attn + ((size_t)bh * Sc + qt + arow) * Sc;
    #pragma unroll
    for (int k2 = 0; k2 < 8; ++k2) {
        const int kt = kh * 8 + k2;
        short8 ra = *(const short8*)&band[arow * 1024 + (kt * 8 + (g ^ asw)) * 8];
        float o[8];
        #pragma unroll
        for (int jj = 0; jj < 8; ++jj) o[jj] = bf2f((u16)ra[jj]) * inv;
        *(float4*)&arowp[kt * 64 + g * 8]     = *(float4*)&o[0];
        *(float4*)&arowp[kt * 64 + g * 8 + 4] = *(float4*)&o[4];
    }
    __syncthreads();                      // band reads done -> reuse as overlay

    // ---------------- O reduce across kf (overlay) and write -------------
    float* ovl = (float*)band;            // [kf][32 rows][stride 68]
    #pragma unroll
    for (int reg = 0; reg < 4; ++reg) {
        const int rowO = rf * 16 + lhi * 4 + reg;
        #pragma unroll
        for (int fd = 0; fd < 4; ++fd)
            ovl[(kf * 32 + rowO) * 68 + fd * 16 + lrow] = acc[fd][reg];
    }
    __syncthreads();

    const int orow_ = tid >> 4;           // 0..31
    const int dq    = tid & 15;           // 4 d per thread
    const float lr = 1.f / (s_lp[0][orow_] + s_lp[1][orow_]
                          + s_lp[2][orow_] + s_lp[3][orow_]);
    u16 t4[4];
    #pragma unroll
    for (int dd = 0; dd < 4; ++dd) {
        const int d = dq * 4 + dd;
        float v = ovl[(0 * 32 + orow_) * 68 + d] + ovl[(1 * 32 + orow_) * 68 + d]
                + ovl[(2 * 32 + orow_) * 68 + d] + ovl[(3 * 32 + orow_) * 68 + d];
        t4[dd] = f2bf(v * lr);
    }
    *(uint2*)&Omid[((size_t)b * Sc + qt + orow_) * Ec + h * HDc + dq * 4] = *(uint2*)t4;
}

// ---------------------------------------------------------------------------
// K4: out = Omid @ Wo^T + bo (f32 out). T1 swizzle (256 blocks, 32/XCD).
// ---------------------------------------------------------------------------
__global__ __launch_bounds__(256, 2) void k_proj(
    const u16* __restrict__ Ob, const u16* __restrict__ Wob,
    const float* __restrict__ bo, float* __restrict__ out)
{
    __shared__ u16 Xs[128 * 64];
    __shared__ u16 Ws[64 * 64];

    const int lbid = (blockIdx.x & 7) * 32 + (blockIdx.x >> 3);  // T1 swizzle
    const int mt = (lbid >> 4) * 128;
    const int et = (lbid & 15) * 64;

    const int tid = threadIdx.x;
    const int w = tid >> 6, lane = tid & 63;
    const int lrow = lane & 15, lhi = lane >> 4;

    f32x4 acc[2][4] = {};

    for (int kb = 0; kb < Ec; kb += 64) {
        #pragma unroll
        for (int it = 0; it < 4; ++it) {
            int idx = tid + it * 256;
            int r = idx >> 3, g = idx & 7;
            *(short8*)&Xs[r * 64 + (g ^ (r & 7)) * 8] =
                *(const short8*)&Ob[(size_t)(mt + r) * Ec + kb + g * 8];
        }
        #pragma unroll
        for (int it = 0; it < 2; ++it) {
            int idx = tid + it * 256;
            int r = idx >> 3, g = idx & 7;
            *(short8*)&Ws[r * 64 + (g ^ (r & 7)) * 8] =
                *(const short8*)&Wob[(size_t)(et + r) * Ec + kb + g * 8];
        }
        __syncthreads();

        #pragma unroll
        for (int ks = 0; ks < 2; ++ks) {
            short8 af[2], bfr[4];
            int g = ks * 4 + lhi;
            #pragma unroll
            for (int fq = 0; fq < 2; ++fq) {
                int rq = w * 32 + fq * 16 + lrow;
                af[fq] = *(const short8*)&Xs[rq * 64 + (g ^ (rq & 7)) * 8];
            }
            #pragma unroll
            for (int fd = 0; fd < 4; ++fd) {
                int rv = fd * 16 + lrow;
                bfr[fd] = *(const short8*)&Ws[rv * 64 + (g ^ (rv & 7)) * 8];
            }
            #pragma unroll
            for (int fq = 0; fq < 2; ++fq)
                #pragma unroll
                for (int fd = 0; fd < 4; ++fd)
                    acc[fq][fd] = __builtin_amdgcn_mfma_f32_16x16x32_bf16(
                        af[fq], bfr[fd], acc[fq][fd], 0, 0, 0);
        }
        __syncthreads();
    }

    #pragma unroll
    for (int fq = 0; fq < 2; ++fq)
        #pragma unroll
        for (int r = 0; r < 4; ++r) {
            const int m = mt + w * 32 + fq * 16 + lhi * 4 + r;
            float* orow = out + (size_t)m * Ec + et;
            #pragma unroll
            for (int fd = 0; fd < 4; ++fd) {
                int e = fd * 16 + lrow;
                orow[e] = acc[fq][fd][r] + bo[et + e];
            }
        }
}

// ---------------------------------------------------------------------------
extern "C" void kernel_launch(void* const* d_in, const int* in_sizes, int n_in,
                              void* d_out, int out_size, void* d_ws, size_t ws_size,
                              hipStream_t stream) {
    const float* query  = (const float*)d_in[0];
    const float* key    = (const float*)d_in[1];
    const float* value  = (const float*)d_in[2];
    const float* aid    = (const float*)d_in[3];
    const float* mw     = (const float*)d_in[4];
    const float* mb     = (const float*)d_in[5];
    const float* Wo     = (const float*)d_in[6];
    const float* bo     = (const float*)d_in[7];
    const float* ascale = (const float*)d_in[8];

    float* out_p  = (float*)d_out;                       // (B,S,E)
    float* attn_p = out_p + (size_t)Bc * Sc * Ec;        // (B,H,S,S)
    float* pre_p  = attn_p + (size_t)Bc * Hc * Sc * Sc;  // (B,H,S,S)

    u16* Vtb  = (u16*)d_ws;                        // 2M elems (transposed V)
    u16* Omid = Vtb  + (size_t)2 * 1024 * 1024;    // 2M
    u16* Qb   = Omid + (size_t)2 * 1024 * 1024;    // 2M
    u16* Kb   = Qb   + (size_t)2 * 1024 * 1024;    // 2M
    u16* Wob  = Kb   + (size_t)2 * 1024 * 1024;    // 1M

    k_prep<<<3072, 256, 0, stream>>>(query, key, Wo, value, Qb, Kb, Wob, Vtb);
    k_scores<<<Bc * 16 * 16, 256, 0, stream>>>(Qb, Kb, aid, mw, mb, ascale, pre_p);
    k_spv<<<Bc * Hc * (Sc / 32), 512, 0, stream>>>(pre_p, Vtb, attn_p, Omid);
    k_proj<<<(Bc * Sc / 128) * (Ec / 64), 256, 0, stream>>>(Omid, Wob, bo, out_p);
}

// Round 16
// 131.668 us; speedup vs baseline: 1.2462x; 1.1951x over previous
//
#include <hip/hip_runtime.h>
#include <hip/hip_bf16.h>

using u16 = unsigned short;
typedef __attribute__((ext_vector_type(8))) short short8;   // 8 bf16 = 4 VGPR
typedef __attribute__((ext_vector_type(4))) float f32x4;

constexpr int Bc = 2, Sc = 1024, Ec = 1024, Hc = 16, HDc = 64;
constexpr float SCALE = 0.125f; // HD^-0.5

// f32 -> bf16 round-to-nearest-even
__device__ __forceinline__ u16 f2bf(float f) {
    union { float f; unsigned u; } v{f};
    unsigned r = v.u + 0x7FFF + ((v.u >> 16) & 1);
    return (u16)(r >> 16);
}
__device__ __forceinline__ float bf2f(u16 x) {
    union { unsigned u; float f; } v; v.u = ((unsigned)x) << 16; return v.f;
}

// ---------------------------------------------------------------------------
// P0 (merged): bid<2560 -> f32->bf16 copies of Q/K/Wo; bid>=2560 -> V transpose
// into Vt[bh][d=64][S=1024] bf16. grid 3072, block 256.
// ---------------------------------------------------------------------------
__global__ __launch_bounds__(256) void k_prep(
    const float* __restrict__ Q, const float* __restrict__ K,
    const float* __restrict__ Wo, const float* __restrict__ V,
    u16* __restrict__ Qb, u16* __restrict__ Kb, u16* __restrict__ Wob,
    u16* __restrict__ Vt)
{
    __shared__ float tile[64][65];
    const int bid = blockIdx.x;
    const int tid = threadIdx.x;

    if (bid < 2560) {
        const float* src; u16* dst; int base;
        if (bid < 1024)      { src = Q;  dst = Qb;  base = bid; }
        else if (bid < 2048) { src = K;  dst = Kb;  base = bid - 1024; }
        else                 { src = Wo; dst = Wob; base = bid - 2048; }
        const int i = (base * 256 + tid) * 8;
        float4 a = *(const float4*)&src[i];
        float4 b = *(const float4*)&src[i + 4];
        u16 t[8] = {f2bf(a.x), f2bf(a.y), f2bf(a.z), f2bf(a.w),
                    f2bf(b.x), f2bf(b.y), f2bf(b.z), f2bf(b.w)};
        *(short8*)&dst[i] = *(short8*)t;
        return;
    }

    const int bx = bid - 2560;           // 0..511
    const int bh = bx >> 4;
    const int k0 = (bx & 15) * 64;
    const float* Vp = V + (size_t)bh * Sc * HDc + (size_t)k0 * HDc;

    #pragma unroll
    for (int it = 0; it < 4; ++it) {
        int idx = tid + it * 256;
        int k = idx >> 4, d4 = idx & 15;
        float4 v = *(const float4*)&Vp[k * HDc + d4 * 4];
        tile[d4 * 4 + 0][k] = v.x;
        tile[d4 * 4 + 1][k] = v.y;
        tile[d4 * 4 + 2][k] = v.z;
        tile[d4 * 4 + 3][k] = v.w;
    }
    __syncthreads();

    u16* Op = Vt + (size_t)bh * HDc * Sc + k0;
    #pragma unroll
    for (int it = 0; it < 4; ++it) {
        int idx = tid + it * 256;
        int d = idx >> 4, kq = idx & 15;
        u16 t[4];
        #pragma unroll
        for (int j = 0; j < 4; ++j) t[j] = f2bf(tile[d][kq * 4 + j]);
        *(uint2*)&Op[(size_t)d * Sc + kq * 4] = *(uint2*)t;
    }
}

// ---------------------------------------------------------------------------
// K1: scores + aid-mixer, ALL 16 HEADS per block; aid in regs read once.
// LDS-staged Q/K with head-loop register prefetch (round-12 proven form).
// T1 XCD swizzle. grid 512 = B*16*16, block 256 = 4 waves.
// ---------------------------------------------------------------------------
__global__ __launch_bounds__(256, 2) void k_scores(
    const u16* __restrict__ Qb, const u16* __restrict__ Kb,
    const float* __restrict__ aid, const float* __restrict__ mw,
    const float* __restrict__ mb, const float* __restrict__ ascale,
    float* __restrict__ pre)
{
    __shared__ u16 Qs[64 * 64];
    __shared__ u16 Ks[64 * 64];

    const int lbid = (blockIdx.x & 7) * 64 + (blockIdx.x >> 3);  // T1 swizzle
    const int kt = lbid & 15;
    const int qt = (lbid >> 4) & 15;
    const int b  = lbid >> 8;

    const int tid = threadIdx.x;
    const int w = tid >> 6, lane = tid & 63;
    const int lrow = lane & 15, lhi = lane >> 4;

    float a3[4][4][3];
    #pragma unroll
    for (int r = 0; r < 4; ++r) {
        const size_t qg = (size_t)(b * Sc + qt * 64 + w * 16 + lhi * 4 + r) * Sc;
        #pragma unroll
        for (int fk = 0; fk < 4; ++fk) {
            const float* ap = aid + (qg + kt * 64 + fk * 16 + lrow) * 3;
            float2 t2 = *(const float2*)ap;
            a3[r][fk][0] = t2.x; a3[r][fk][1] = t2.y; a3[r][fk][2] = ap[2];
        }
    }

    const float asc = ascale[0];
    const u16* Qbase = Qb + ((size_t)b * Hc * Sc + qt * 64) * HDc;
    const u16* Kbase = Kb + ((size_t)b * Hc * Sc + kt * 64) * HDc;

    const int r0 = tid >> 3,          g0 = tid & 7;
    const int r1 = (tid + 256) >> 3,  g1 = tid & 7;
    const int gs0 = (g0 ^ (r0 & 7)) * 8;
    const int gs1 = (g1 ^ (r1 & 7)) * 8;

    short8 qp0, qp1, kp0, kp1;
    {
        qp0 = *(const short8*)&Qbase[r0 * 64 + g0 * 8];
        qp1 = *(const short8*)&Qbase[r1 * 64 + g1 * 8];
        kp0 = *(const short8*)&Kbase[r0 * 64 + g0 * 8];
        kp1 = *(const short8*)&Kbase[r1 * 64 + g1 * 8];
    }

    for (int h = 0; h < Hc; ++h) {
        *(short8*)&Qs[r0 * 64 + gs0] = qp0;
        *(short8*)&Qs[r1 * 64 + gs1] = qp1;
        *(short8*)&Ks[r0 * 64 + gs0] = kp0;
        *(short8*)&Ks[r1 * 64 + gs1] = kp1;
        __syncthreads();

        if (h < Hc - 1) {
            const u16* Qp = Qbase + (size_t)(h + 1) * Sc * HDc;
            const u16* Kp = Kbase + (size_t)(h + 1) * Sc * HDc;
            qp0 = *(const short8*)&Qp[r0 * 64 + g0 * 8];
            qp1 = *(const short8*)&Qp[r1 * 64 + g1 * 8];
            kp0 = *(const short8*)&Kp[r0 * 64 + g0 * 8];
            kp1 = *(const short8*)&Kp[r1 * 64 + g1 * 8];
        }

        f32x4 acc[4] = {};
        #pragma unroll
        for (int ks2 = 0; ks2 < 2; ++ks2) {
            const int rq = w * 16 + lrow;
            short8 af = *(const short8*)&Qs[rq * 64 + ((ks2 * 4 + lhi) ^ (rq & 7)) * 8];
            #pragma unroll
            for (int fk = 0; fk < 4; ++fk) {
                const int rk = fk * 16 + lrow;
                short8 bf = *(const short8*)&Ks[rk * 64 + ((ks2 * 4 + lhi) ^ (rk & 7)) * 8];
                acc[fk] = __builtin_amdgcn_mfma_f32_16x16x32_bf16(af, bf, acc[fk], 0, 0, 0);
            }
        }

        const float w0 = mw[h * 4 + 0], w1 = mw[h * 4 + 1];
        const float w2 = mw[h * 4 + 2], w3 = mw[h * 4 + 3];
        const float bias = mb[h];
        float* prow0 = pre + ((size_t)(b * Hc + h) * Sc + qt * 64 + w * 16 + lhi * 4) * Sc
                     + kt * 64 + lrow;
        #pragma unroll
        for (int r = 0; r < 4; ++r) {
            #pragma unroll
            for (int fk = 0; fk < 4; ++fk) {
                float s = acc[fk][r] * SCALE;
                float mm = s * w0 + a3[r][fk][0] * w1 + a3[r][fk][1] * w2
                         + a3[r][fk][2] * w3 + bias;
                prow0[(size_t)r * Sc + fk * 16] = s + fmaxf(mm, 0.f) * asc;
            }
        }
        __syncthreads();
    }
}

// ---------------------------------------------------------------------------
// K2: fused softmax + attn-write + PV, 32-row bands, EXP-ONCE.
// T1 swizzle. Regular cached loads/stores (round-12 proven form).
// ---------------------------------------------------------------------------
__global__ __launch_bounds__(512, 4) void k_spv(
    const float* __restrict__ pre, const u16* __restrict__ Vt,
    float* __restrict__ attn, u16* __restrict__ Omid)
{
    __shared__ u16 band[32 * 1024];       // 64 KiB; f32 overlay at the end
    __shared__ float s_m[32];
    __shared__ float s_lp[4][32];         // per-kf partial row sums

    const int lbid = (blockIdx.x & 7) * 128 + (blockIdx.x >> 3);  // T1 swizzle
    const int bh  = lbid >> 5;
    const int qt  = (lbid & 31) * 32;
    const int b   = bh >> 4, h = bh & 15;

    const int tid  = threadIdx.x;
    const int w    = tid >> 6, lane = tid & 63;
    const int lrow = lane & 15, lhi = lane >> 4;

    // ---------------- Phase A: stream pre, track max, fill band ----------
    const int arow = tid >> 4;            // 0..31
    const int s16  = tid & 15;
    const int g    = s16 & 7;
    const int kh   = s16 >> 3;
    const int asw  = arow & 7;
    const float* prow = pre + ((size_t)bh * Sc + qt + arow) * Sc;
    float m = -1e30f;
    #pragma unroll
    for (int k2 = 0; k2 < 8; ++k2) {
        const int kt = kh * 8 + k2;
        const float* p0 = prow + kt * 64 + g * 8;
        float s[8];
        *(float4*)&s[0] = *(const float4*)p0;
        *(float4*)&s[4] = *(const float4*)(p0 + 4);
        u16 t[8];
        #pragma unroll
        for (int j = 0; j < 8; ++j) { m = fmaxf(m, s[j]); t[j] = f2bf(s[j]); }
        *(short8*)&band[arow * 1024 + (kt * 8 + (g ^ asw)) * 8] = *(short8*)t;
    }
    m = fmaxf(m, __shfl_xor(m, 1));
    m = fmaxf(m, __shfl_xor(m, 2));
    m = fmaxf(m, __shfl_xor(m, 4));
    m = fmaxf(m, __shfl_xor(m, 8));
    if (s16 == 0) s_m[arow] = m;
    __syncthreads();

    // ------- Phase B: exp once, write back, partial l, PV accumulate -----
    const int rf = w & 1, kf = w >> 1;    // row-frag 0..1, k-range 0..3
    const int brow = rf * 16 + lrow;
    const int bsw  = brow & 7;
    const float mreg = s_m[brow];
    const u16* Vbase = Vt + (size_t)bh * HDc * Sc;
    float l = 0.f;
    f32x4 acc[4] = {};

    #pragma unroll
    for (int j = 0; j < 4; ++j) {
        const int kt = kf * 4 + j;
        const int soA = brow * 1024 + (kt * 8 + (lhi ^ bsw)) * 8;
        const int soB = brow * 1024 + (kt * 8 + ((lhi + 4) ^ bsw)) * 8;
        short8 ra = *(const short8*)&band[soA];
        short8 rb = *(const short8*)&band[soB];
        u16 ea[8], eb[8];
        #pragma unroll
        for (int jj = 0; jj < 8; ++jj) {
            float va = __expf(bf2f((u16)ra[jj]) - mreg); l += va; ea[jj] = f2bf(va);
            float vb = __expf(bf2f((u16)rb[jj]) - mreg); l += vb; eb[jj] = f2bf(vb);
        }
        *(short8*)&band[soA] = *(short8*)ea;   // write exp'd values back
        *(short8*)&band[soB] = *(short8*)eb;
        short8 A0 = *(short8*)ea, A1 = *(short8*)eb;
        #pragma unroll
        for (int fd = 0; fd < 4; ++fd) {
            const u16* vp = Vbase + (size_t)(fd * 16 + lrow) * Sc + kt * 64;
            short8 b0 = *(const short8*)&vp[lhi * 8];
            short8 b1 = *(const short8*)&vp[(lhi + 4) * 8];
            acc[fd] = __builtin_amdgcn_mfma_f32_16x16x32_bf16(A0, b0, acc[fd], 0, 0, 0);
            acc[fd] = __builtin_amdgcn_mfma_f32_16x16x32_bf16(A1, b1, acc[fd], 0, 0, 0);
        }
    }
    l += __shfl_xor(l, 16);
    l += __shfl_xor(l, 32);
    if (lhi == 0) s_lp[kf][brow] = l;
    __syncthreads();                      // exp'd band + s_lp visible

    // ---------------- Phase C: attn = band * inv (no exp) ----------------
    const float lt = s_lp[0][arow] + s_lp[1][arow] + s_lp[2][arow] + s_lp[3][arow];
    const float inv = 1.f / lt;
    float* arowp = attn + ((size_t)bh * Sc + qt + arow) * Sc;
    #pragma unroll
    for (int k2 = 0; k2 < 8; ++k2) {
        const int kt = kh * 8 + k2;
        short8 ra = *(const short8*)&band[arow * 1024 + (kt * 8 + (g ^ asw)) * 8];
        float o[8];
        #pragma unroll
        for (int jj = 0; jj < 8; ++jj) o[jj] = bf2f((u16)ra[jj]) * inv;
        *(float4*)&arowp[kt * 64 + g * 8]     = *(float4*)&o[0];
        *(float4*)&arowp[kt * 64 + g * 8 + 4] = *(float4*)&o[4];
    }
    __syncthreads();                      // band reads done -> reuse as overlay

    // ---------------- O reduce across kf (overlay) and write -------------
    float* ovl = (float*)band;            // [kf][32 rows][stride 68]
    #pragma unroll
    for (int reg = 0; reg < 4; ++reg) {
        const int rowO = rf * 16 + lhi * 4 + reg;
        #pragma unroll
        for (int fd = 0; fd < 4; ++fd)
            ovl[(kf * 32 + rowO) * 68 + fd * 16 + lrow] = acc[fd][reg];
    }
    __syncthreads();

    const int orow_ = tid >> 4;           // 0..31
    const int dq    = tid & 15;           // 4 d per thread
    const float lr = 1.f / (s_lp[0][orow_] + s_lp[1][orow_]
                          + s_lp[2][orow_] + s_lp[3][orow_]);
    u16 t4[4];
    #pragma unroll
    for (int dd = 0; dd < 4; ++dd) {
        const int d = dq * 4 + dd;
        float v = ovl[(0 * 32 + orow_) * 68 + d] + ovl[(1 * 32 + orow_) * 68 + d]
                + ovl[(2 * 32 + orow_) * 68 + d] + ovl[(3 * 32 + orow_) * 68 + d];
        t4[dd] = f2bf(v * lr);
    }
    *(uint2*)&Omid[((size_t)b * Sc + qt + orow_) * Ec + h * HDc + dq * 4] = *(uint2*)t4;
}

// ---------------------------------------------------------------------------
// K4: out = Omid @ Wo^T + bo (f32 out). NEW: 64x64 tiles, grid 512 =
// 2 blocks/CU (was 256 = 1/CU, 1 wave/SIMD -> no latency hiding).
// T1 swizzle (512 blocks, 64/XCD).
// ---------------------------------------------------------------------------
__global__ __launch_bounds__(256, 2) void k_proj(
    const u16* __restrict__ Ob, const u16* __restrict__ Wob,
    const float* __restrict__ bo, float* __restrict__ out)
{
    __shared__ u16 Xs[64 * 64];
    __shared__ u16 Ws[64 * 64];

    const int lbid = (blockIdx.x & 7) * 64 + (blockIdx.x >> 3);  // T1 swizzle
    const int mt = (lbid >> 4) * 64;
    const int et = (lbid & 15) * 64;

    const int tid = threadIdx.x;
    const int w = tid >> 6, lane = tid & 63;
    const int lrow = lane & 15, lhi = lane >> 4;

    f32x4 acc[4] = {};

    for (int kb = 0; kb < Ec; kb += 64) {
        #pragma unroll
        for (int it = 0; it < 2; ++it) {
            int idx = tid + it * 256;
            int r = idx >> 3, g = idx & 7;
            int gs = (g ^ (r & 7)) * 8;
            *(short8*)&Xs[r * 64 + gs] =
                *(const short8*)&Ob[(size_t)(mt + r) * Ec + kb + g * 8];
            *(short8*)&Ws[r * 64 + gs] =
                *(const short8*)&Wob[(size_t)(et + r) * Ec + kb + g * 8];
        }
        __syncthreads();

        #pragma unroll
        for (int ks = 0; ks < 2; ++ks) {
            const int rq = w * 16 + lrow;
            short8 af = *(const short8*)&Xs[rq * 64 + ((ks * 4 + lhi) ^ (rq & 7)) * 8];
            #pragma unroll
            for (int fd = 0; fd < 4; ++fd) {
                const int rv = fd * 16 + lrow;
                short8 bf = *(const short8*)&Ws[rv * 64 + ((ks * 4 + lhi) ^ (rv & 7)) * 8];
                acc[fd] = __builtin_amdgcn_mfma_f32_16x16x32_bf16(af, bf, acc[fd], 0, 0, 0);
            }
        }
        __syncthreads();
    }

    #pragma unroll
    for (int r = 0; r < 4; ++r) {
        const int m = mt + w * 16 + lhi * 4 + r;
        float* orow = out + (size_t)m * Ec + et;
        #pragma unroll
        for (int fd = 0; fd < 4; ++fd) {
            int e = fd * 16 + lrow;
            orow[e] = acc[fd][r] + bo[et + e];
        }
    }
}

// ---------------------------------------------------------------------------
extern "C" void kernel_launch(void* const* d_in, const int* in_sizes, int n_in,
                              void* d_out, int out_size, void* d_ws, size_t ws_size,
                              hipStream_t stream) {
    const float* query  = (const float*)d_in[0];
    const float* key    = (const float*)d_in[1];
    const float* value  = (const float*)d_in[2];
    const float* aid    = (const float*)d_in[3];
    const float* mw     = (const float*)d_in[4];
    const float* mb     = (const float*)d_in[5];
    const float* Wo     = (const float*)d_in[6];
    const float* bo     = (const float*)d_in[7];
    const float* ascale = (const float*)d_in[8];

    float* out_p  = (float*)d_out;                       // (B,S,E)
    float* attn_p = out_p + (size_t)Bc * Sc * Ec;        // (B,H,S,S)
    float* pre_p  = attn_p + (size_t)Bc * Hc * Sc * Sc;  // (B,H,S,S)

    u16* Vtb  = (u16*)d_ws;                        // 2M elems (transposed V)
    u16* Omid = Vtb  + (size_t)2 * 1024 * 1024;    // 2M
    u16* Qb   = Omid + (size_t)2 * 1024 * 1024;    // 2M
    u16* Kb   = Qb   + (size_t)2 * 1024 * 1024;    // 2M
    u16* Wob  = Kb   + (size_t)2 * 1024 * 1024;    // 1M

    k_prep<<<3072, 256, 0, stream>>>(query, key, Wo, value, Qb, Kb, Wob, Vtb);
    k_scores<<<Bc * 16 * 16, 256, 0, stream>>>(Qb, Kb, aid, mw, mb, ascale, pre_p);
    k_spv<<<Bc * Hc * (Sc / 32), 512, 0, stream>>>(pre_p, Vtb, attn_p, Omid);
    k_proj<<<(Bc * Sc / 64) * (Ec / 64), 256, 0, stream>>>(Omid, Wob, bo, out_p);
}